// Round 7
// baseline (155.912 us; speedup 1.0000x reference)
//
#include <hip/hip_runtime.h>

namespace {
constexpr int B = 8, C = 64, H = 128, W = 128;
constexpr int HW  = H * W;
constexpr int CHW = C * HW;
}

// One block per (b, h) row: phase 1 computes softmax affinities for the row's 128
// pixels into LDS; phase 2 applies them to x for all 64 channels. No workspace.
// Block: 256 thr = 32 w-chunks (4 px) x 8 channel-groups (8 ch).
__global__ __launch_bounds__(256, 4) void fused_row_kernel(const float* __restrict__ xs,
                                                           const float* __restrict__ xx,
                                                           float* __restrict__ out)
{
    __shared__ float part[8][32][33];   // phase-1 partials, stride 33 -> conflict-free
    __shared__ float affs[128][9];      // row affinities, stride 9

    const int t  = threadIdx.x;
    const int ck = t & 31;              // w-chunk: pixels w4..w4+3
    const int cg = t >> 5;              // channel group (8 ch)

    // XCD-chunked swizzle: round-robin dispatch (lin % 8 -> XCD) becomes
    // h-contiguous per XCD; XCD j owns batch j entirely -> halo rows L2-hit.
    const int lin = blockIdx.x;                      // 0..1023
    const int hb  = (lin >> 3) + (lin & 7) * 128;    // bijective
    const int h   = hb & (H - 1);
    const int b   = hb >> 7;

    const int w4 = ck * 4;
    const bool ft = (h == 0), fb = (h == H - 1), fl = (ck == 0), fr = (ck == 31);
    const int oT = ft ? 0 : -W;          // clamped offsets; values zeroed below
    const int oB = fb ? 0 :  W;
    const int oL = fl ? 0 : -1;
    const int oR = fr ? 3 :  4;

    // ---------------- Phase 1: affinity logits for this row ----------------
    {
        const float* base = xs + (size_t)b * CHW + (size_t)cg * 8 * HW + h * W + w4;
        float p[4][8];
#pragma unroll
        for (int i = 0; i < 4; ++i)
#pragma unroll
            for (int k = 0; k < 8; ++k) p[i][k] = 0.f;

#pragma unroll
        for (int c = 0; c < 8; ++c) {
            const float* pc = base + (size_t)c * HW;
            float4 m4 = *(const float4*)pc;
            float4 t4 = *(const float4*)(pc + oT);
            float4 b4 = *(const float4*)(pc + oB);
            float tl = pc[oT + oL], tr = pc[oT + oR];
            float ml = pc[oL],      mr = pc[oR];
            float bl = pc[oB + oL], br = pc[oB + oR];
            if (ft) { t4.x = t4.y = t4.z = t4.w = 0.f; tl = 0.f; tr = 0.f; }
            if (fb) { b4.x = b4.y = b4.z = b4.w = 0.f; bl = 0.f; br = 0.f; }
            if (fl) { tl = 0.f; ml = 0.f; bl = 0.f; }
            if (fr) { tr = 0.f; mr = 0.f; br = 0.f; }
            const float T[6]  = {tl, t4.x, t4.y, t4.z, t4.w, tr};
            const float M[6]  = {ml, m4.x, m4.y, m4.z, m4.w, mr};
            const float Bo[6] = {bl, b4.x, b4.y, b4.z, b4.w, br};
            const float ce[4] = {m4.x, m4.y, m4.z, m4.w};
#pragma unroll
            for (int i = 0; i < 4; ++i) {
                p[i][0] = fmaf(ce[i], T[i],      p[i][0]);
                p[i][1] = fmaf(ce[i], T[i + 1],  p[i][1]);
                p[i][2] = fmaf(ce[i], T[i + 2],  p[i][2]);
                p[i][3] = fmaf(ce[i], M[i],      p[i][3]);
                p[i][4] = fmaf(ce[i], M[i + 2],  p[i][4]);
                p[i][5] = fmaf(ce[i], Bo[i],     p[i][5]);
                p[i][6] = fmaf(ce[i], Bo[i + 1], p[i][6]);
                p[i][7] = fmaf(ce[i], Bo[i + 2], p[i][7]);
            }
        }
#pragma unroll
        for (int i = 0; i < 4; ++i)
#pragma unroll
            for (int k = 0; k < 8; ++k) part[cg][ck][i * 8 + k] = p[i][k];
    }
    __syncthreads();

    // ---------------- Reduce + softmax (threads 0..127, one pixel each) ----------------
    if (t < 128) {
        const int c2 = t >> 2, px = t & 3;   // pixel w = t
        float v[8];
#pragma unroll
        for (int k = 0; k < 8; ++k) {
            float s = 0.f;
#pragma unroll
            for (int g = 0; g < 8; ++g) s += part[g][c2][px * 8 + k];
            v[k] = s;
        }
        float m = v[0];
#pragma unroll
        for (int k = 1; k < 8; ++k) m = fmaxf(m, v[k]);
        float s = 0.f;
#pragma unroll
        for (int k = 0; k < 8; ++k) { v[k] = __expf(v[k] - m); s += v[k]; }
        const float inv = 1.f / s;
#pragma unroll
        for (int k = 0; k < 8; ++k) affs[t][k] = v[k] * inv;
    }
    __syncthreads();

    // ---------------- Phase 2: apply to x (8 ch x 4 px per thread) ----------------
    float a[4][8];
#pragma unroll
    for (int i = 0; i < 4; ++i)
#pragma unroll
        for (int k = 0; k < 8; ++k) a[i][k] = affs[w4 + i][k];

    const float* pxb = xx  + (size_t)b * CHW + (size_t)cg * 8 * HW + h * W + w4;
    float*       pob = out + (size_t)b * CHW + (size_t)cg * 8 * HW + h * W + w4;
#pragma unroll
    for (int c = 0; c < 8; ++c) {
        const float* pc = pxb + (size_t)c * HW;
        float4 m4 = *(const float4*)pc;
        float4 t4 = *(const float4*)(pc + oT);
        float4 b4 = *(const float4*)(pc + oB);
        float tl = pc[oT + oL], tr = pc[oT + oR];
        float ml = pc[oL],      mr = pc[oR];
        float bl = pc[oB + oL], br = pc[oB + oR];
        if (ft) { t4.x = t4.y = t4.z = t4.w = 0.f; tl = 0.f; tr = 0.f; }
        if (fb) { b4.x = b4.y = b4.z = b4.w = 0.f; bl = 0.f; br = 0.f; }
        if (fl) { tl = 0.f; ml = 0.f; bl = 0.f; }
        if (fr) { tr = 0.f; mr = 0.f; br = 0.f; }
        const float T[6]  = {tl, t4.x, t4.y, t4.z, t4.w, tr};
        const float M[6]  = {ml, m4.x, m4.y, m4.z, m4.w, mr};
        const float Bo[6] = {bl, b4.x, b4.y, b4.z, b4.w, br};
        float r[4];
#pragma unroll
        for (int i = 0; i < 4; ++i) {
            float acc = a[i][0] * T[i];
            acc = fmaf(a[i][1], T[i + 1],  acc);
            acc = fmaf(a[i][2], T[i + 2],  acc);
            acc = fmaf(a[i][3], M[i],      acc);
            acc = fmaf(a[i][4], M[i + 2],  acc);
            acc = fmaf(a[i][5], Bo[i],     acc);
            acc = fmaf(a[i][6], Bo[i + 1], acc);
            acc = fmaf(a[i][7], Bo[i + 2], acc);
            r[i] = acc;
        }
        *(float4*)(pob + (size_t)c * HW) = make_float4(r[0], r[1], r[2], r[3]);
    }
}

extern "C" void kernel_launch(void* const* d_in, const int* in_sizes, int n_in,
                              void* d_out, int out_size, void* d_ws, size_t ws_size,
                              hipStream_t stream) {
    const float* xs = (const float*)d_in[0];   // x_stem
    const float* xx = (const float*)d_in[1];   // x
    float* out = (float*)d_out;
    (void)d_ws; (void)ws_size;

    fused_row_kernel<<<dim3(H * B), 256, 0, stream>>>(xs, xx, out);
}

// Round 8
// 137.395 us; speedup vs baseline: 1.1348x; 1.1348x over previous
//
#include <hip/hip_runtime.h>

namespace {
constexpr int B = 8, C = 64, H = 128, W = 128;
constexpr int HW  = H * W;
constexpr int CHW = C * HW;
}

// ---------------- K1: affinity logits (4-way channel split) + softmax -> aff[pix][8] ----------------
// Round-5 proven version: scalar clamped loads, 2048 blocks, 100% occupancy.
__global__ __launch_bounds__(256) void aff_kernel(const float* __restrict__ xs,
                                                  float* __restrict__ aff)
{
    __shared__ float part[4][64][9];   // stride 9 -> conflict-free

    const int tid = threadIdx.x;
    const int tx  = tid & 63;
    const int cg  = tid >> 6;          // channel group 0..3 (16 ch each)
    const int w   = blockIdx.x * 64 + tx;
    const int h   = blockIdx.y;
    const int b   = blockIdx.z;

    const bool hm = h > 0, hp = h < H - 1, wm = w > 0, wp = w < W - 1;
    // clamped offsets: OOB neighbors read a valid (wrong) element, logits zeroed after
    const int om = hm ? -W : 0;
    const int op = hp ?  W : 0;
    const int cm = wm ? -1 : 0;
    const int cp = wp ?  1 : 0;
    const int o0 = om + cm, o1 = om, o2 = om + cp, o3 = cm,
              o4 = cp, o5 = op + cm, o6 = op, o7 = op + cp;

    const float* pc = xs + (size_t)b * CHW + (size_t)cg * 16 * HW + h * W + w;

    float a0 = 0, a1 = 0, a2 = 0, a3 = 0, a4 = 0, a5 = 0, a6 = 0, a7 = 0;
#pragma unroll
    for (int c = 0; c < 16; ++c, pc += HW) {
        const float ce = pc[0];
        a0 = fmaf(ce, pc[o0], a0);
        a1 = fmaf(ce, pc[o1], a1);
        a2 = fmaf(ce, pc[o2], a2);
        a3 = fmaf(ce, pc[o3], a3);
        a4 = fmaf(ce, pc[o4], a4);
        a5 = fmaf(ce, pc[o5], a5);
        a6 = fmaf(ce, pc[o6], a6);
        a7 = fmaf(ce, pc[o7], a7);
    }
    // mask once: OOB logit must be exactly 0 (zero-pad dot product) before softmax
    a0 = (hm && wm) ? a0 : 0.f;
    a1 = hm         ? a1 : 0.f;
    a2 = (hm && wp) ? a2 : 0.f;
    a3 = wm         ? a3 : 0.f;
    a4 = wp         ? a4 : 0.f;
    a5 = (hp && wm) ? a5 : 0.f;
    a6 = hp         ? a6 : 0.f;
    a7 = (hp && wp) ? a7 : 0.f;

    float* pp = &part[cg][tx][0];
    pp[0] = a0; pp[1] = a1; pp[2] = a2; pp[3] = a3;
    pp[4] = a4; pp[5] = a5; pp[6] = a6; pp[7] = a7;
    __syncthreads();

    if (tid < 64) {
        float v[8];
#pragma unroll
        for (int k = 0; k < 8; ++k)
            v[k] = part[0][tid][k] + part[1][tid][k] + part[2][tid][k] + part[3][tid][k];
        float m = v[0];
#pragma unroll
        for (int k = 1; k < 8; ++k) m = fmaxf(m, v[k]);
        float s = 0.f;
#pragma unroll
        for (int k = 0; k < 8; ++k) { v[k] = __expf(v[k] - m); s += v[k]; }
        const float inv = 1.f / s;
        const size_t pix = (size_t)b * HW + h * W + (blockIdx.x * 64 + tid);
        float4 f0 = make_float4(v[0] * inv, v[1] * inv, v[2] * inv, v[3] * inv);
        float4 f1 = make_float4(v[4] * inv, v[5] * inv, v[6] * inv, v[7] * inv);
        *(float4*)(aff + pix * 8)     = f0;
        *(float4*)(aff + pix * 8 + 4) = f1;
    }
}

// ---------------- K2: 4 px x 4 ch per thread, vectorized stencil; grid.x = C/32 ----------------
// Round-6 version: aff re-read 2x (8 MB) instead of 8x; 3.5x fewer VMEM requests.
__global__ __launch_bounds__(256) void apply_kernel(const float* __restrict__ xx,
                                                    const float* __restrict__ aff,
                                                    float* __restrict__ out)
{
    const int t  = threadIdx.x;
    const int ck = t & 31;
    const int cs = t >> 5;
    const int h  = blockIdx.y;
    const int b  = blockIdx.z;
    const int c0 = blockIdx.x * 32 + cs * 4;
    const int w4 = ck * 4;

    const bool ft = (h == 0), fb = (h == H - 1), fl = (ck == 0), fr = (ck == 31);
    const int oT = ft ? 0 : -W;
    const int oB = fb ? 0 :  W;
    const int oL = fl ? 0 : -1;
    const int oR = fr ? 3 :  4;

    // per-pixel softmax weights a[px][k]
    const float* pa = aff + ((size_t)b * HW + h * W + w4) * 8;
    float a[4][8];
#pragma unroll
    for (int i = 0; i < 4; ++i) {
        const float4 lo = *(const float4*)(pa + i * 8);
        const float4 hi = *(const float4*)(pa + i * 8 + 4);
        a[i][0] = lo.x; a[i][1] = lo.y; a[i][2] = lo.z; a[i][3] = lo.w;
        a[i][4] = hi.x; a[i][5] = hi.y; a[i][6] = hi.z; a[i][7] = hi.w;
    }

    const float* pxb = xx  + (size_t)b * CHW + (size_t)c0 * HW + h * W + w4;
    float*       pob = out + (size_t)b * CHW + (size_t)c0 * HW + h * W + w4;
#pragma unroll
    for (int c = 0; c < 4; ++c) {
        const float* pc = pxb + (size_t)c * HW;
        float4 m4 = *(const float4*)pc;
        float4 t4 = *(const float4*)(pc + oT);
        float4 b4 = *(const float4*)(pc + oB);
        float tl = pc[oT + oL], tr = pc[oT + oR];
        float ml = pc[oL],      mr = pc[oR];
        float bl = pc[oB + oL], br = pc[oB + oR];
        if (ft) { t4.x = t4.y = t4.z = t4.w = 0.f; tl = 0.f; tr = 0.f; }
        if (fb) { b4.x = b4.y = b4.z = b4.w = 0.f; bl = 0.f; br = 0.f; }
        if (fl) { tl = 0.f; ml = 0.f; bl = 0.f; }
        if (fr) { tr = 0.f; mr = 0.f; br = 0.f; }
        const float T[6]  = {tl, t4.x, t4.y, t4.z, t4.w, tr};
        const float M[6]  = {ml, m4.x, m4.y, m4.z, m4.w, mr};
        const float Bo[6] = {bl, b4.x, b4.y, b4.z, b4.w, br};
        float r[4];
#pragma unroll
        for (int i = 0; i < 4; ++i) {
            float acc = a[i][0] * T[i];
            acc = fmaf(a[i][1], T[i + 1],  acc);
            acc = fmaf(a[i][2], T[i + 2],  acc);
            acc = fmaf(a[i][3], M[i],      acc);
            acc = fmaf(a[i][4], M[i + 2],  acc);
            acc = fmaf(a[i][5], Bo[i],     acc);
            acc = fmaf(a[i][6], Bo[i + 1], acc);
            acc = fmaf(a[i][7], Bo[i + 2], acc);
            r[i] = acc;
        }
        *(float4*)(pob + (size_t)c * HW) = make_float4(r[0], r[1], r[2], r[3]);
    }
}

extern "C" void kernel_launch(void* const* d_in, const int* in_sizes, int n_in,
                              void* d_out, int out_size, void* d_ws, size_t ws_size,
                              hipStream_t stream) {
    const float* xs = (const float*)d_in[0];   // x_stem
    const float* xx = (const float*)d_in[1];   // x
    float* out = (float*)d_out;
    float* aff = (float*)d_ws;                 // 8*B*HW floats = 4 MiB

    aff_kernel<<<dim3(2, H, B), 256, 0, stream>>>(xs, aff);
    apply_kernel<<<dim3(C / 32, H, B), 256, 0, stream>>>(xx, aff, out);
}

// Round 9
// 127.404 us; speedup vs baseline: 1.2238x; 1.0784x over previous
//
#include <hip/hip_runtime.h>

namespace {
constexpr int B = 8, C = 64, H = 128, W = 128;
constexpr int HW  = H * W;
constexpr int CHW = C * HW;
constexpr int BHW = B * HW;
}

// ---------------- K1: affinity logits (4-way channel split) + softmax -> aff[pix][8] ----------------
__global__ __launch_bounds__(256) void aff_kernel(const float* __restrict__ xs,
                                                  float* __restrict__ aff)
{
    __shared__ float part[4][64][9];   // stride 9 -> conflict-free

    const int tid = threadIdx.x;
    const int tx  = tid & 63;
    const int cg  = tid >> 6;          // channel group 0..3 (16 ch each)
    const int w   = blockIdx.x * 64 + tx;
    const int h   = blockIdx.y;
    const int b   = blockIdx.z;

    const bool hm = h > 0, hp = h < H - 1, wm = w > 0, wp = w < W - 1;
    // clamped offsets: OOB neighbors read a valid (wrong) element, zeroed after the loop
    const int om = hm ? -W : 0;
    const int op = hp ?  W : 0;
    const int cm = wm ? -1 : 0;
    const int cp = wp ?  1 : 0;
    const int o0 = om + cm, o1 = om, o2 = om + cp, o3 = cm,
              o4 = cp, o5 = op + cm, o6 = op, o7 = op + cp;

    const float* pc = xs + (size_t)b * CHW + (size_t)cg * 16 * HW + h * W + w;

    float a0 = 0, a1 = 0, a2 = 0, a3 = 0, a4 = 0, a5 = 0, a6 = 0, a7 = 0;
#pragma unroll
    for (int c = 0; c < 16; ++c, pc += HW) {
        const float ce = pc[0];
        a0 = fmaf(ce, pc[o0], a0);
        a1 = fmaf(ce, pc[o1], a1);
        a2 = fmaf(ce, pc[o2], a2);
        a3 = fmaf(ce, pc[o3], a3);
        a4 = fmaf(ce, pc[o4], a4);
        a5 = fmaf(ce, pc[o5], a5);
        a6 = fmaf(ce, pc[o6], a6);
        a7 = fmaf(ce, pc[o7], a7);
    }
    // mask once: OOB logit must be exactly 0 (zero-pad dot product) before softmax
    a0 = (hm && wm) ? a0 : 0.f;
    a1 = hm         ? a1 : 0.f;
    a2 = (hm && wp) ? a2 : 0.f;
    a3 = wm         ? a3 : 0.f;
    a4 = wp         ? a4 : 0.f;
    a5 = (hp && wm) ? a5 : 0.f;
    a6 = hp         ? a6 : 0.f;
    a7 = (hp && wp) ? a7 : 0.f;

    float* pp = &part[cg][tx][0];
    pp[0] = a0; pp[1] = a1; pp[2] = a2; pp[3] = a3;
    pp[4] = a4; pp[5] = a5; pp[6] = a6; pp[7] = a7;
    __syncthreads();

    if (tid < 64) {
        float v[8];
#pragma unroll
        for (int k = 0; k < 8; ++k)
            v[k] = part[0][tid][k] + part[1][tid][k] + part[2][tid][k] + part[3][tid][k];
        float m = v[0];
#pragma unroll
        for (int k = 1; k < 8; ++k) m = fmaxf(m, v[k]);
        float s = 0.f;
#pragma unroll
        for (int k = 0; k < 8; ++k) { v[k] = __expf(v[k] - m); s += v[k]; }
        const float inv = 1.f / s;
        const size_t pix = (size_t)b * HW + h * W + (blockIdx.x * 64 + tid);
        float4 f0 = make_float4(v[0] * inv, v[1] * inv, v[2] * inv, v[3] * inv);
        float4 f1 = make_float4(v[4] * inv, v[5] * inv, v[6] * inv, v[7] * inv);
        *(float4*)(aff + pix * 8)     = f0;
        *(float4*)(aff + pix * 8 + 4) = f1;
    }
}

// ---------------- K2: out[b,c,h,w] = sum_k aff[pix][k] * x_nbr_k ; 4 channels/thread ----------------
__global__ __launch_bounds__(256) void apply_kernel(const float* __restrict__ xx,
                                                    const float* __restrict__ aff,
                                                    float* __restrict__ out)
{
    const int tid = threadIdx.x;
    const int w   = tid & 127;
    const int cq  = tid >> 7;                    // 0/1
    const int c0  = blockIdx.x * 8 + cq * 4;     // 4 channels per thread
    const int h   = blockIdx.y;
    const int b   = blockIdx.z;

    const bool hm = h > 0, hp = h < H - 1, wm = w > 0, wp = w < W - 1;
    const int om = hm ? -W : 0;
    const int op = hp ?  W : 0;
    const int cm = wm ? -1 : 0;
    const int cp = wp ?  1 : 0;
    const int o0 = om + cm, o1 = om, o2 = om + cp, o3 = cm,
              o4 = cp, o5 = op + cm, o6 = op, o7 = op + cp;

    const size_t pix = (size_t)b * HW + h * W + w;
    const float4 f0 = *(const float4*)(aff + pix * 8);
    const float4 f1 = *(const float4*)(aff + pix * 8 + 4);
    // zero the weights of OOB neighbors once; clamped loads then contribute 0
    const float a0 = (hm && wm) ? f0.x : 0.f;
    const float a1 = hm         ? f0.y : 0.f;
    const float a2 = (hm && wp) ? f0.z : 0.f;
    const float a3 = wm         ? f0.w : 0.f;
    const float a4 = wp         ? f1.x : 0.f;
    const float a5 = (hp && wm) ? f1.y : 0.f;
    const float a6 = hp         ? f1.z : 0.f;
    const float a7 = (hp && wp) ? f1.w : 0.f;

    const float* px = xx  + (size_t)b * CHW + (size_t)c0 * HW + h * W + w;
    float*       po = out + (size_t)b * CHW + (size_t)c0 * HW + h * W + w;
#pragma unroll
    for (int c = 0; c < 4; ++c, px += HW, po += HW) {
        float acc = a0 * px[o0];
        acc = fmaf(a1, px[o1], acc);
        acc = fmaf(a2, px[o2], acc);
        acc = fmaf(a3, px[o3], acc);
        acc = fmaf(a4, px[o4], acc);
        acc = fmaf(a5, px[o5], acc);
        acc = fmaf(a6, px[o6], acc);
        acc = fmaf(a7, px[o7], acc);
        po[0] = acc;
    }
}

extern "C" void kernel_launch(void* const* d_in, const int* in_sizes, int n_in,
                              void* d_out, int out_size, void* d_ws, size_t ws_size,
                              hipStream_t stream) {
    const float* xs = (const float*)d_in[0];   // x_stem
    const float* xx = (const float*)d_in[1];   // x
    float* out = (float*)d_out;
    float* aff = (float*)d_ws;                 // 8*BHW floats = 4 MiB (ws is 256 MiB)

    aff_kernel<<<dim3(2, H, B), 256, 0, stream>>>(xs, aff);
    apply_kernel<<<dim3(C / 8, H, B), 256, 0, stream>>>(xx, aff, out);
}